// Round 6
// baseline (146.291 us; speedup 1.0000x reference)
//
#include <hip/hip_runtime.h>
#include <hip/hip_bf16.h>

#define NN 1024
#define LN_EPS 1e-5f

typedef __bf16 bf16x8 __attribute__((ext_vector_type(8)));
typedef float floatx4 __attribute__((ext_vector_type(4)));
typedef float floatx2 __attribute__((ext_vector_type(2)));

__device__ __forceinline__ floatx4 splat4(float s) { return (floatx4){s, s, s, s}; }

// Kernel 1 (blocks 0..63): per-node precompute, 16 nodes/block (4 per wave) so
// W1 streams once per 4 nodes (128 MB total vs 512 MB at 1 node/pass).
//   Ap[i][h] = emb[i]·W1[:64,h] + b1[h]   (f32 row-major; uniform -> s_load in fused)
//   Bf[j][h] = emb[j]·W1[64:,h]           (f32 ROW-major: per-lane contiguous rows)
//   sumA/sumB/sumA2/sumB2: per-node Σ and Σ² (LN1 stats: Σx²=ΣA²+2<A,B>+ΣB²)
// Block 64: wave 0 packs W2^T into MFMA A-frag order (bf16).
__global__ __launch_bounds__(256) void precompute_ab(
    const float* __restrict__ emb, const float* __restrict__ W1,
    const float* __restrict__ b1, const float* __restrict__ W2,
    float* __restrict__ Ap, float* __restrict__ Bf,
    float* __restrict__ sumA, float* __restrict__ sumB,
    float* __restrict__ sumA2, float* __restrict__ sumB2,
    __bf16* __restrict__ Wf) {
    int tid = threadIdx.x, wv = tid >> 6, lane = tid & 63;
    if (blockIdx.x == 64) {
        if (wv != 0) return;
        // A-frag for mfma_f32_16x16x32_bf16: lane l holds A[m][k], m=l&15, k=(l>>4)*8+t.
        int m_l = lane & 15, kg = lane >> 4;
#pragma unroll
        for (int mt = 0; mt < 4; mt++)
#pragma unroll
            for (int kc = 0; kc < 2; kc++) {
                bf16x8 f;
#pragma unroll
                for (int t = 0; t < 8; t++) {
                    int k = kc * 32 + kg * 8 + t;
                    f[t] = (__bf16)W2[k * 64 + mt * 16 + m_l];
                }
                *(bf16x8*)&Wf[((mt * 2 + kc) * 64 + lane) * 8] = f;
            }
        return;
    }
    __shared__ __align__(16) float e[16][64];
    int nb = blockIdx.x * 16 + wv * 4;
#pragma unroll
    for (int n = 0; n < 4; n++) e[wv * 4 + n][lane] = emb[(nb + n) * 64 + lane];
    // same-wave LDS write->read: drain DS (+VMEM feeding it) before cross-lane reads
    asm volatile("s_waitcnt vmcnt(0) lgkmcnt(0)" ::: "memory");

    float b1l = b1[lane];
    float a0 = b1l, a1 = b1l, a2 = b1l, a3 = b1l;
    float c0 = 0.f, c1 = 0.f, c2 = 0.f, c3 = 0.f;
    const float* w1a = W1 + lane;
    const float* w1b = W1 + 64 * 64 + lane;
#pragma unroll 16
    for (int d = 0; d < 64; d++) {
        float wa = w1a[d * 64];
        float wb = w1b[d * 64];
        float e0 = e[wv * 4 + 0][d], e1v = e[wv * 4 + 1][d];
        float e2v = e[wv * 4 + 2][d], e3v = e[wv * 4 + 3][d];
        a0 = fmaf(e0, wa, a0); a1 = fmaf(e1v, wa, a1);
        a2 = fmaf(e2v, wa, a2); a3 = fmaf(e3v, wa, a3);
        c0 = fmaf(e0, wb, c0); c1 = fmaf(e1v, wb, c1);
        c2 = fmaf(e2v, wb, c2); c3 = fmaf(e3v, wb, c3);
    }
    float va[4] = {a0, a1, a2, a3}, vb[4] = {c0, c1, c2, c3};
#pragma unroll
    for (int n = 0; n < 4; n++) {
        int node = nb + n;
        Ap[node * 64 + lane] = va[n];
        Bf[node * 64 + lane] = vb[n];
        float ra = va[n], rb = vb[n], ra2 = va[n] * va[n], rb2 = vb[n] * vb[n];
#pragma unroll
        for (int off = 1; off < 64; off <<= 1) {
            ra += __shfl_xor(ra, off);
            rb += __shfl_xor(rb, off);
            ra2 += __shfl_xor(ra2, off);
            rb2 += __shfl_xor(rb2, off);
        }
        if (lane == 0) { sumA[node] = ra; sumB[node] = rb; sumA2[node] = ra2; sumB2[node] = rb2; }
    }
}

// Kernel 2: fused pair-MLP. Block=256 (4 waves), block b: i=b>>2, wave w covers
// j in [(b&3)*256+w*64, +64). Lane = pair.
// Stage 1: per-lane contiguous B-row loads (1 addr calc + imm offsets);
// LN1 stats via precomputed sums + in-lane f32 dot <A,B> (no x[64] live range,
// no AGPR parking). Single fused normalize pass re-reads the L1-hot row.
// LDS = h1 tile only (32768 B), zero block barriers, b2-in-acc init.
__global__ __launch_bounds__(256, 4) void fused(
    const float* __restrict__ Ap, const float* __restrict__ Bf, const __bf16* __restrict__ Wf,
    const float* __restrict__ sumA, const float* __restrict__ sumB,
    const float* __restrict__ sumA2, const float* __restrict__ sumB2,
    const float* __restrict__ g1, const float* __restrict__ be1, const float* __restrict__ b2,
    const float* __restrict__ g2, const float* __restrict__ be2, const float* __restrict__ W3,
    const float* __restrict__ b3, const float* __restrict__ mask, float* __restrict__ out) {
    __shared__ __align__(16) __bf16 h1t[4][64 * 64];  // 32768 B; per-wave 8KB, XOR-swizzled

    int tid = threadIdx.x;
    int wave = tid >> 6, lane = tid & 63;
    int i = blockIdx.x >> 2;
    int j0 = (blockIdx.x & 3) * 256 + wave * 64;
    int jme = j0 + lane;

    int m_l = lane & 15, kg = lane >> 4;
    const float* Arow = Ap + i * 64;        // uniform -> scalar loads
    const float* brow = Bf + jme * 64;      // per-lane row, contiguous (imm offsets)

    // ---- Stage 1: <A,B_j> dot (16 dwordx4 + 32 pk-fma), stats from sums ----
    floatx4 dacc = splat4(0.f);
#pragma unroll
    for (int c = 0; c < 16; c++) {
        floatx4 bb = *(const floatx4*)(brow + c * 4);
        floatx4 aa = *(const floatx4*)&Arow[c * 4];
        dacc = aa * bb + dacc;
    }
    float dot = (dacc[0] + dacc[1]) + (dacc[2] + dacc[3]);
    float m1 = (sumA[i] + sumB[jme]) * 0.015625f;
    float sq = fmaf(2.f, dot, sumA2[i] + sumB2[jme]);
    float rs1 = rsqrtf(fmaf(m1, -m1, sq * 0.015625f) + LN_EPS);
    floatx4 RS = splat4(rs1), OF = splat4(-m1 * rs1);

    // W2^T fragments, coalesced from prepacked buffer
    bf16x8 afrag[4][2];
#pragma unroll
    for (int mt = 0; mt < 4; mt++)
#pragma unroll
        for (int kc = 0; kc < 2; kc++)
            afrag[mt][kc] = *(const bf16x8*)&Wf[((mt * 2 + kc) * 64 + lane) * 8];

    // ---- Single-pass LN1 + ReLU -> bf16 LDS row (L1-hot reload of brow) ----
    __bf16* rowp = &h1t[wave][lane * 64];
    int sw = lane & 7;
#pragma unroll
    for (int c = 0; c < 8; c++) {
        floatx4 b0 = *(const floatx4*)(brow + c * 8);
        floatx4 b1v = *(const floatx4*)(brow + c * 8 + 4);
        floatx4 a0 = *(const floatx4*)&Arow[c * 8];
        floatx4 a1 = *(const floatx4*)&Arow[c * 8 + 4];
        floatx4 g0 = *(const floatx4*)&g1[c * 8];       // uniform -> scalar
        floatx4 g1r = *(const floatx4*)&g1[c * 8 + 4];
        floatx4 e0 = *(const floatx4*)&be1[c * 8];
        floatx4 e1r = *(const floatx4*)&be1[c * 8 + 4];
        floatx4 y0 = ((a0 + b0) * RS + OF) * g0 + e0;
        floatx4 y1 = ((a1 + b1v) * RS + OF) * g1r + e1r;
        y0 = __builtin_elementwise_max(y0, splat4(0.f));
        y1 = __builtin_elementwise_max(y1, splat4(0.f));
        bf16x8 fr;
        fr[0] = (__bf16)y0[0]; fr[1] = (__bf16)y0[1]; fr[2] = (__bf16)y0[2]; fr[3] = (__bf16)y0[3];
        fr[4] = (__bf16)y1[0]; fr[5] = (__bf16)y1[1]; fr[6] = (__bf16)y1[2]; fr[7] = (__bf16)y1[3];
        *(bf16x8*)(rowp + ((c ^ sw) * 8)) = fr;
    }
    // wave-private tile: drain DS before cross-lane reads (no block barrier)
    asm volatile("s_waitcnt lgkmcnt(0)" ::: "memory");

    // ---- MFMA: pre2^T = W2^T @ h1^T, accumulator initialized with b2 ----
    floatx4 b2r[4];
#pragma unroll
    for (int mt = 0; mt < 4; mt++) b2r[mt] = *(const floatx4*)&b2[mt * 16 + kg * 4];
    floatx4 acc[4][4];
#pragma unroll
    for (int mt = 0; mt < 4; mt++)
#pragma unroll
        for (int nt = 0; nt < 4; nt++) acc[mt][nt] = b2r[mt];

    const __bf16* wbase = &h1t[wave][0];
#pragma unroll
    for (int nt = 0; nt < 4; nt++) {
        int pair = nt * 16 + m_l;
#pragma unroll
        for (int kc = 0; kc < 2; kc++) {
            int chunk = kc * 4 + kg;
            bf16x8 bfrag = *(const bf16x8*)(wbase + pair * 64 + ((chunk ^ (pair & 7)) * 8));
#pragma unroll
            for (int mt = 0; mt < 4; mt++)
                acc[mt][nt] =
                    __builtin_amdgcn_mfma_f32_16x16x32_bf16(afrag[mt][kc], bfrag, acc[mt][nt], 0, 0, 0);
        }
    }

    // ---- Epilogue params hoisted to regs (afrag dead now) ----
    floatx4 g2r[4], e2r[4], w3r[4];
#pragma unroll
    for (int mt = 0; mt < 4; mt++) {
        g2r[mt] = *(const floatx4*)&g2[mt * 16 + kg * 4];
        e2r[mt] = *(const floatx4*)&be2[mt * 16 + kg * 4];
        w3r[mt] = *(const floatx4*)&W3[mt * 16 + kg * 4];
    }
    float b3v = b3[0];

    // ---- LN2 + ReLU + W3 dot + mask. Lane holds h'=mt*16+kg*4+r, pair=nt*16+m_l ----
#pragma unroll
    for (int nt = 0; nt < 4; nt++) {
        floatx2 s2v = {0.f, 0.f}, q2v = {0.f, 0.f};
#pragma unroll
        for (int mt = 0; mt < 4; mt++) {
            floatx2 vlo = {acc[mt][nt][0], acc[mt][nt][1]};
            floatx2 vhi = {acc[mt][nt][2], acc[mt][nt][3]};
            s2v += vlo; s2v += vhi;
            q2v += vlo * vlo; q2v += vhi * vhi;
        }
        float s2 = s2v[0] + s2v[1];
        float q2 = q2v[0] + q2v[1];
        s2 += __shfl_xor(s2, 16); s2 += __shfl_xor(s2, 32);
        q2 += __shfl_xor(q2, 16); q2 += __shfl_xor(q2, 32);
        float m2 = s2 * 0.015625f;
        float rs2 = rsqrtf(fmaf(m2, -m2, q2 * 0.015625f) + LN_EPS);
        floatx2 P2 = {rs2, rs2};
        float o2s = -m2 * rs2;
        floatx2 O2 = {o2s, o2s};

        floatx2 scv = {0.f, 0.f};
#pragma unroll
        for (int mt = 0; mt < 4; mt++) {
#pragma unroll
            for (int hh = 0; hh < 2; hh++) {
                floatx2 v = {acc[mt][nt][2 * hh], acc[mt][nt][2 * hh + 1]};
                floatx2 g = {g2r[mt][2 * hh], g2r[mt][2 * hh + 1]};
                floatx2 e = {e2r[mt][2 * hh], e2r[mt][2 * hh + 1]};
                floatx2 w = {w3r[mt][2 * hh], w3r[mt][2 * hh + 1]};
                floatx2 y = (v * P2 + O2) * g + e;
                y = __builtin_elementwise_max(y, (floatx2){0.f, 0.f});
                scv += y * w;
            }
        }
        float sc = scv[0] + scv[1];
        sc += __shfl_xor(sc, 16); sc += __shfl_xor(sc, 32);

        if (kg == 0) {
            int j = j0 + nt * 16 + m_l;
            int p = i * NN + j;
            out[p] = (i == j) ? 0.f : (sc + b3v) * mask[p];
        }
    }
}

extern "C" void kernel_launch(void* const* d_in, const int* in_sizes, int n_in,
                              void* d_out, int out_size, void* d_ws, size_t ws_size,
                              hipStream_t stream) {
    const float* emb = (const float*)d_in[0];
    const float* mask = (const float*)d_in[1];
    const float* W1 = (const float*)d_in[2];
    const float* b1 = (const float*)d_in[3];
    const float* g1 = (const float*)d_in[4];
    const float* be1 = (const float*)d_in[5];
    const float* W2 = (const float*)d_in[6];
    const float* b2 = (const float*)d_in[7];
    const float* g2 = (const float*)d_in[8];
    const float* be2 = (const float*)d_in[9];
    const float* W3 = (const float*)d_in[10];
    const float* b3 = (const float*)d_in[11];
    float* out = (float*)d_out;

    float* Ap = (float*)d_ws;                 // 256 KB
    float* Bf = Ap + 65536;                   // 256 KB (row-major B)
    float* sA = Bf + 65536;                   // 4 KB
    float* sB = sA + 1024;                    // 4 KB
    float* sA2 = sB + 1024;                   // 4 KB
    float* sB2 = sA2 + 1024;                  // 4 KB
    __bf16* Wf = (__bf16*)(sB2 + 1024);       // 8 KB

    precompute_ab<<<65, 256, 0, stream>>>(emb, W1, b1, W2, Ap, Bf, sA, sB, sA2, sB2, Wf);
    fused<<<4096, 256, 0, stream>>>(Ap, Bf, Wf, sA, sB, sA2, sB2,
                                    g1, be1, b2, g2, be2, W3, b3, mask, out);
}

// Round 7
// 134.464 us; speedup vs baseline: 1.0880x; 1.0880x over previous
//
#include <hip/hip_runtime.h>
#include <hip/hip_bf16.h>

#define NN 1024
#define LN_EPS 1e-5f

typedef __bf16 bf16x8 __attribute__((ext_vector_type(8)));
typedef float floatx4 __attribute__((ext_vector_type(4)));
typedef float floatx2 __attribute__((ext_vector_type(2)));

__device__ __forceinline__ floatx4 splat4(float s) { return (floatx4){s, s, s, s}; }

// Kernel 1 (blocks 0..1023): per-node precompute.
//   Ap[i][h] = emb[i]·W1[:64,h] + b1[h]  (f32 row-major; uniform -> s_load in fused)
//   Bt[h][j] = emb[j]·W1[64:,h]          (f32 transposed — COALESCED lane=j walks)
//   Abf/Bbf  = bf16 row-major copies (for the dot GEMM)
//   sums: ΣA, ΣB, ΣA², ΣB² per node  (LN1 stats: Σx² = ΣA² + 2<A,B> + ΣB²)
// Block 1024: Wf = W2^T packed in MFMA A-frag order; Wc[k]=Σ_h' W2[k][h']; sb2=Σb2.
__global__ void precompute_ab(const float* __restrict__ emb, const float* __restrict__ W1,
                              const float* __restrict__ b1, const float* __restrict__ W2,
                              const float* __restrict__ b2,
                              float* __restrict__ Ap, float* __restrict__ Bt,
                              __bf16* __restrict__ Abf, __bf16* __restrict__ Bbf,
                              float* __restrict__ sumA, float* __restrict__ sumB,
                              float* __restrict__ sumA2, float* __restrict__ sumB2,
                              float* __restrict__ Wc, float* __restrict__ sb2,
                              __bf16* __restrict__ Wf) {
    int lane = threadIdx.x;
    if (blockIdx.x == 1024) {
        // A-frag for mfma_f32_16x16x32_bf16: lane l holds A[m][k], m=l&15, k=(l>>4)*8+t.
        int m_l = lane & 15, kg = lane >> 4;
#pragma unroll
        for (int mt = 0; mt < 4; mt++)
#pragma unroll
            for (int kc = 0; kc < 2; kc++) {
                bf16x8 f;
#pragma unroll
                for (int t = 0; t < 8; t++) {
                    int k = kc * 32 + kg * 8 + t;
                    f[t] = (__bf16)W2[k * 64 + mt * 16 + m_l];
                }
                *(bf16x8*)&Wf[((mt * 2 + kc) * 64 + lane) * 8] = f;
            }
        float s = 0.f;
        for (int h = 0; h < 64; h++) s += W2[lane * 64 + h];
        Wc[lane] = s;
        float v = b2[lane];
#pragma unroll
        for (int off = 1; off < 64; off <<= 1) v += __shfl_xor(v, off);
        if (lane == 0) sb2[0] = v;
        return;
    }
    __shared__ __align__(16) float e[64];
    int i = blockIdx.x, h = lane;
    e[h] = emb[i * 64 + h];
    __syncthreads();
    float a = b1[h], b = 0.f;
#pragma unroll
    for (int d = 0; d < 64; d++) {
        a = fmaf(e[d], W1[d * 64 + h], a);
        b = fmaf(e[d], W1[(64 + d) * 64 + h], b);
    }
    Ap[i * 64 + h] = a;
    Bt[h * NN + i] = b;
    Abf[i * 64 + h] = (__bf16)a;
    Bbf[i * 64 + h] = (__bf16)b;
    float ra = a, rb = b, ra2 = a * a, rb2 = b * b;
#pragma unroll
    for (int off = 1; off < 64; off <<= 1) {
        ra += __shfl_xor(ra, off);
        rb += __shfl_xor(rb, off);
        ra2 += __shfl_xor(ra2, off);
        rb2 += __shfl_xor(rb2, off);
    }
    if (h == 0) { sumA[i] = ra; sumB[i] = rb; sumA2[i] = ra2; sumB2[i] = rb2; }
}

// Kernel 2: dotM[i][j] = <A_i, B_j> via MFMA (1024x1024x64 GEMM, bf16 in, f32 out).
// 256 tiles of 64x64; 64 blocks x 4 waves, one tile per wave.
__global__ __launch_bounds__(256) void dotgemm(const __bf16* __restrict__ Abf,
                                               const __bf16* __restrict__ Bbf,
                                               float* __restrict__ dotM) {
    int tid = threadIdx.x, wave = tid >> 6, lane = tid & 63;
    int t = blockIdx.x * 4 + wave;          // 0..255
    int ibase = (t >> 4) * 64, jbase = (t & 15) * 64;
    int m_l = lane & 15, kg = lane >> 4;

    floatx4 acc[4][4];
#pragma unroll
    for (int mt = 0; mt < 4; mt++)
#pragma unroll
        for (int nt = 0; nt < 4; nt++) acc[mt][nt] = splat4(0.f);

#pragma unroll
    for (int kc = 0; kc < 2; kc++) {
        bf16x8 af[4], bf[4];
#pragma unroll
        for (int mt = 0; mt < 4; mt++)
            af[mt] = *(const bf16x8*)&Abf[(ibase + mt * 16 + m_l) * 64 + kc * 32 + kg * 8];
#pragma unroll
        for (int nt = 0; nt < 4; nt++)
            bf[nt] = *(const bf16x8*)&Bbf[(jbase + nt * 16 + m_l) * 64 + kc * 32 + kg * 8];
#pragma unroll
        for (int mt = 0; mt < 4; mt++)
#pragma unroll
            for (int nt = 0; nt < 4; nt++)
                acc[mt][nt] = __builtin_amdgcn_mfma_f32_16x16x32_bf16(af[mt], bf[nt], acc[mt][nt], 0, 0, 0);
    }
    // C/D: col = lane&15 (j), row = (lane>>4)*4 + r (i)
#pragma unroll
    for (int mt = 0; mt < 4; mt++)
#pragma unroll
        for (int nt = 0; nt < 4; nt++)
#pragma unroll
            for (int r = 0; r < 4; r++) {
                int gi = ibase + mt * 16 + kg * 4 + r;
                int gj = jbase + nt * 16 + m_l;
                dotM[gi * NN + gj] = acc[mt][nt][r];
            }
}

// Kernel 3: fused pair-MLP. Block=256 (4 waves), block b: i=b>>2, wave w covers
// j in [(b&3)*256+w*64, +64). Lane = pair (walks contiguous j: ALL loads coalesced).
// rs1 from precomputed sums + dotM (one coalesced load) -> LN1 is a SINGLE pass,
// no x[64] live range, no AGPR parking. s2 (LN2 mean) linearized via Wc during LN1.
// LDS = h1 tile only (32768 B), zero block barriers, b2-in-acc init.
__global__ __launch_bounds__(256, 4) void fused(
    const float* __restrict__ Ap, const float* __restrict__ Bt, const __bf16* __restrict__ Wf,
    const float* __restrict__ dotM,
    const float* __restrict__ sumA, const float* __restrict__ sumB,
    const float* __restrict__ sumA2, const float* __restrict__ sumB2,
    const float* __restrict__ Wcp, const float* __restrict__ sb2p,
    const float* __restrict__ g1, const float* __restrict__ be1, const float* __restrict__ b2,
    const float* __restrict__ g2, const float* __restrict__ be2, const float* __restrict__ W3,
    const float* __restrict__ b3, const float* __restrict__ mask, float* __restrict__ out) {
    __shared__ __align__(16) __bf16 h1t[4][64 * 64];  // 32768 B; per-wave 8KB, XOR-swizzled

    int tid = threadIdx.x;
    int wave = tid >> 6, lane = tid & 63;
    int i = blockIdx.x >> 2;
    int j0 = (blockIdx.x & 3) * 256 + wave * 64;
    int jme = j0 + lane;

    int m_l = lane & 15, kg = lane >> 4;
    const float* Arow = Ap + i * 64;        // uniform -> scalar loads
    const float* btp = Bt + jme;            // coalesced column walk

    // ---- LN1 stats: all precomputed (1 coalesced load + scalar sums) ----
    float dot = dotM[i * NN + jme];
    float m1 = (sumA[i] + sumB[jme]) * 0.015625f;
    float sq = fmaf(2.f, dot, sumA2[i] + sumB2[jme]);
    float rs1 = rsqrtf(fmaf(m1, -m1, sq * 0.015625f) + LN_EPS);
    floatx2 P1 = {rs1, rs1};
    float ofs = -m1 * rs1;
    floatx2 O1 = {ofs, ofs};

    // W2^T fragments, coalesced from prepacked buffer
    bf16x8 afrag[4][2];
#pragma unroll
    for (int mt = 0; mt < 4; mt++)
#pragma unroll
        for (int kc = 0; kc < 2; kc++)
            afrag[mt][kc] = *(const bf16x8*)&Wf[((mt * 2 + kc) * 64 + lane) * 8];

    // ---- SINGLE-pass LN1 + ReLU + s2p-dot -> bf16 LDS row (XOR-swizzled) ----
    __bf16* rowp = &h1t[wave][lane * 64];
    int sw = lane & 7;
    floatx2 s2acc = {0.f, 0.f};
#pragma unroll
    for (int c = 0; c < 8; c++) {
        bf16x8 fr;
#pragma unroll
        for (int t = 0; t < 4; t++) {
            int h = c * 8 + 2 * t;
            floatx2 bb = { btp[h * NN], btp[(h + 1) * NN] };          // coalesced
            floatx2 aa = *(const floatx2*)&Arow[h];                    // scalar
            floatx2 gg = *(const floatx2*)&g1[h];                      // scalar
            floatx2 ee = *(const floatx2*)&be1[h];                     // scalar
            floatx2 wc = *(const floatx2*)&Wcp[h];                     // scalar
            floatx2 y = ((aa + bb) * P1 + O1) * gg + ee;
            y = __builtin_elementwise_max(y, (floatx2){0.f, 0.f});
            s2acc += y * wc;
            fr[2 * t]     = (__bf16)y[0];
            fr[2 * t + 1] = (__bf16)y[1];
        }
        *(bf16x8*)(rowp + ((c ^ sw) * 8)) = fr;
    }
    float s2p = (s2acc[0] + s2acc[1]) + sb2p[0];   // Σ_h'(pre2+b2) for this lane's pair
    // wave-private tile: drain DS before cross-lane reads (no block barrier)
    asm volatile("s_waitcnt lgkmcnt(0)" ::: "memory");

    // ---- MFMA: pre2^T = W2^T @ h1^T, accumulator initialized with b2 ----
    floatx4 b2r[4];
#pragma unroll
    for (int mt = 0; mt < 4; mt++) b2r[mt] = *(const floatx4*)&b2[mt * 16 + kg * 4];
    floatx4 acc[4][4];
#pragma unroll
    for (int mt = 0; mt < 4; mt++)
#pragma unroll
        for (int nt = 0; nt < 4; nt++) acc[mt][nt] = b2r[mt];

    const __bf16* wbase = &h1t[wave][0];
#pragma unroll
    for (int nt = 0; nt < 4; nt++) {
        int pair = nt * 16 + m_l;
#pragma unroll
        for (int kc = 0; kc < 2; kc++) {
            int chunk = kc * 4 + kg;
            bf16x8 bfrag = *(const bf16x8*)(wbase + pair * 64 + ((chunk ^ (pair & 7)) * 8));
#pragma unroll
            for (int mt = 0; mt < 4; mt++)
                acc[mt][nt] =
                    __builtin_amdgcn_mfma_f32_16x16x32_bf16(afrag[mt][kc], bfrag, acc[mt][nt], 0, 0, 0);
        }
    }

    // ---- Epilogue params hoisted to regs (afrag dead now) ----
    floatx4 g2r[4], e2r[4], w3r[4];
#pragma unroll
    for (int mt = 0; mt < 4; mt++) {
        g2r[mt] = *(const floatx4*)&g2[mt * 16 + kg * 4];
        e2r[mt] = *(const floatx4*)&be2[mt * 16 + kg * 4];
        w3r[mt] = *(const floatx4*)&W3[mt * 16 + kg * 4];
    }
    float b3v = b3[0];

    // ---- LN2 + ReLU + W3 dot + mask. Lane holds h'=mt*16+kg*4+r, pair=nt*16+m_l ----
#pragma unroll
    for (int nt = 0; nt < 4; nt++) {
        float s2 = __shfl(s2p, nt * 16 + m_l);   // Σ(pre2+b2) for this lane's pair
        floatx2 q2v = {0.f, 0.f};
#pragma unroll
        for (int mt = 0; mt < 4; mt++) {
            floatx2 vlo = {acc[mt][nt][0], acc[mt][nt][1]};
            floatx2 vhi = {acc[mt][nt][2], acc[mt][nt][3]};
            q2v += vlo * vlo;
            q2v += vhi * vhi;
        }
        float q2 = q2v[0] + q2v[1];
        q2 += __shfl_xor(q2, 16); q2 += __shfl_xor(q2, 32);
        float m2 = s2 * 0.015625f;
        float rs2 = rsqrtf(fmaf(m2, -m2, q2 * 0.015625f) + LN_EPS);
        floatx2 P2 = {rs2, rs2};
        float o2s = -m2 * rs2;
        floatx2 O2 = {o2s, o2s};

        floatx2 scv = {0.f, 0.f};
#pragma unroll
        for (int mt = 0; mt < 4; mt++) {
#pragma unroll
            for (int hh = 0; hh < 2; hh++) {
                floatx2 v = {acc[mt][nt][2 * hh], acc[mt][nt][2 * hh + 1]};
                floatx2 g = {g2r[mt][2 * hh], g2r[mt][2 * hh + 1]};
                floatx2 e = {e2r[mt][2 * hh], e2r[mt][2 * hh + 1]};
                floatx2 w = {w3r[mt][2 * hh], w3r[mt][2 * hh + 1]};
                floatx2 y = (v * P2 + O2) * g + e;
                y = __builtin_elementwise_max(y, (floatx2){0.f, 0.f});
                scv += y * w;
            }
        }
        float sc = scv[0] + scv[1];
        sc += __shfl_xor(sc, 16); sc += __shfl_xor(sc, 32);

        if (kg == 0) {
            int j = j0 + nt * 16 + m_l;
            int p = i * NN + j;
            out[p] = (i == j) ? 0.f : (sc + b3v) * mask[p];
        }
    }
}

extern "C" void kernel_launch(void* const* d_in, const int* in_sizes, int n_in,
                              void* d_out, int out_size, void* d_ws, size_t ws_size,
                              hipStream_t stream) {
    const float* emb = (const float*)d_in[0];
    const float* mask = (const float*)d_in[1];
    const float* W1 = (const float*)d_in[2];
    const float* b1 = (const float*)d_in[3];
    const float* g1 = (const float*)d_in[4];
    const float* be1 = (const float*)d_in[5];
    const float* W2 = (const float*)d_in[6];
    const float* b2 = (const float*)d_in[7];
    const float* g2 = (const float*)d_in[8];
    const float* be2 = (const float*)d_in[9];
    const float* W3 = (const float*)d_in[10];
    const float* b3 = (const float*)d_in[11];
    float* out = (float*)d_out;

    float* Ap = (float*)d_ws;                 // 256 KB
    float* Bt = Ap + 65536;                   // 256 KB (transposed, coalesced)
    float* sA = Bt + 65536;                   // 4 KB
    float* sB = sA + 1024;                    // 4 KB
    float* sA2 = sB + 1024;                   // 4 KB
    float* sB2 = sA2 + 1024;                  // 4 KB
    float* Wc = sB2 + 1024;                   // 256 B
    float* sb2 = Wc + 64;                     // 256 B (pad)
    __bf16* Abf = (__bf16*)(sb2 + 64);        // 128 KB
    __bf16* Bbf = Abf + 65536;                // 128 KB
    __bf16* Wf = Bbf + 65536;                 // 8 KB
    float* dotM = (float*)(Wf + 4096);        // 4 MB
    (void)ws_size;

    precompute_ab<<<1025, 64, 0, stream>>>(emb, W1, b1, W2, b2, Ap, Bt, Abf, Bbf,
                                           sA, sB, sA2, sB2, Wc, sb2, Wf);
    dotgemm<<<64, 256, 0, stream>>>(Abf, Bbf, dotM);
    fused<<<4096, 256, 0, stream>>>(Ap, Bt, Wf, dotM, sA, sB, sA2, sB2, Wc, sb2,
                                    g1, be1, b2, g2, be2, W3, b3, mask, out);
}